// Round 8
// baseline (224.882 us; speedup 1.0000x reference)
//
#include <hip/hip_runtime.h>
#include <stdint.h>

#define NTOK 8192
#define DIM  1024
#define NE   8
#define NPAIR 28
#define OUTD 4096
#define MAXTILES 155   // >= sum_p ceil(cnt_p/64) worst case (128 + 27)

typedef __attribute__((ext_vector_type(8))) short bf16x8;
typedef __attribute__((ext_vector_type(4))) float f32x4;

static __device__ __forceinline__ unsigned short f2bf(float f) {
    uint32_t u = __float_as_uint(f);
    u += 0x7fffu + ((u >> 16) & 1u);     // RNE
    return (unsigned short)(u >> 16);
}

// ---- K0: weight repacks to bf16 (+ zero pairCnt; runs FIRST) ----
// w1m[e][j][k][i]  (k = kb*8+kk), i contiguous  : 524288 elems
// w2m[e][k][l][j]  j contiguous                 : 1048576 elems
__global__ __launch_bounds__(256) void k_wm(const float* __restrict__ W1,
                                            const float* __restrict__ W2,
                                            unsigned short* __restrict__ w1m,
                                            unsigned short* __restrict__ w2m,
                                            int* __restrict__ pairCnt) {
    int t = blockIdx.x * 256 + threadIdx.x;
    if (blockIdx.x == 0 && threadIdx.x < 32) pairCnt[threadIdx.x] = 0;
    if (t < 524288) {
        int i = t & 31, k = (t >> 5) & 63, j = (t >> 11) & 31, e = (t >> 16) & 7;
        w1m[t] = f2bf(W1[(((j * 32 + i) * 64 + k) * 8) + e]);
    } else {
        int t2 = t - 524288;
        int j = t2 & 31, l = (t2 >> 5) & 63, k = (t2 >> 11) & 63, e = (t2 >> 17) & 7;
        w2m[t2] = f2bf(W2[(((e * 64 + k) * 32 + j) * 64) + l]);
    }
}

// ---- K1: gate (fp32) + pair bucketing ----
__global__ __launch_bounds__(256) void k_gate(const float* __restrict__ x,
                                              const float* __restrict__ Wg,
                                              int* __restrict__ pairCnt,
                                              int* __restrict__ bucket,
                                              float* __restrict__ wgt) {
    __shared__ float sWg[NE][DIM];
    int tid = threadIdx.x;
    #pragma unroll
    for (int u = 0; u < 8; ++u) {
        int idx = u * 1024 + tid * 4;
        *(float4*)&sWg[0][idx] = *(const float4*)&Wg[idx];
    }
    __syncthreads();
    int w = tid >> 6, lane = tid & 63;
    int tok = blockIdx.x * 4 + w;
    float acc[NE];
    #pragma unroll
    for (int e = 0; e < NE; ++e) acc[e] = 0.f;
    const float* xr = x + (size_t)tok * DIM;
    #pragma unroll
    for (int c = 0; c < 4; ++c) {
        float4 xv = *(const float4*)&xr[c * 256 + lane * 4];
        #pragma unroll
        for (int e = 0; e < NE; ++e) {
            float4 wv = *(const float4*)&sWg[e][c * 256 + lane * 4];
            acc[e] += xv.x * wv.x + xv.y * wv.y + xv.z * wv.z + xv.w * wv.w;
        }
    }
    #pragma unroll
    for (int e = 0; e < NE; ++e)
        #pragma unroll
        for (int off = 32; off > 0; off >>= 1)
            acc[e] += __shfl_xor(acc[e], off, 64);
    if (lane == 0) {
        int i1 = 0; float v1 = acc[0];
        for (int e = 1; e < NE; ++e) if (acc[e] > v1) { v1 = acc[e]; i1 = e; }
        int i2 = -1; float v2 = -3.4e38f;
        for (int e = 0; e < NE; ++e) { if (e == i1) continue; if (acc[e] > v2) { v2 = acc[e]; i2 = e; } }
        float ex = expf(v2 - v1);
        float s  = 1.f / (1.f + ex);
        float w1v = s + 1e-6f;
        float w2v = ex * s + 1e-6f;
        int ea = min(i1, i2), eb = max(i1, i2);
        float wa = (i1 < i2) ? w1v : w2v;
        float wb = (i1 < i2) ? w2v : w1v;
        wgt[tok * 2 + 0] = wa;
        wgt[tok * 2 + 1] = wb;
        int pid = ea * 7 - (ea * (ea - 1)) / 2 + (eb - ea - 1);
        int pos = atomicAdd(&pairCnt[pid], 1);
        bucket[pid * NTOK + pos] = tok;
    }
}

// ---- K2: slot -> token map + tile descriptors ----
__global__ __launch_bounds__(256) void k_slots(const int* __restrict__ pairCnt,
                                               const int* __restrict__ bucket,
                                               int* __restrict__ tokmap,
                                               int4* __restrict__ tileDesc) {
    int s = blockIdx.x * 256 + threadIdx.x;
    {
        int off = 0;
        for (int p = 0; p < NPAIR; ++p) {
            int c = pairCnt[p];
            if (s < off + c) { tokmap[s] = bucket[p * NTOK + (s - off)]; break; }
            off += c;
        }
    }
    if (s < MAXTILES) {
        int4 d; d.x = -1; d.y = 0; d.z = 0; d.w = 0;
        int toff = 0, soff = 0;
        for (int q = 0; q < NPAIR; ++q) {
            int c = pairCnt[q];
            int nt = (c + 63) >> 6;
            if (d.x < 0 && s < toff + nt) {
                int lt = s - toff;
                d.x = q;
                d.y = soff + lt * 64;
                d.z = min(64, c - lt * 64);
            }
            toff += nt; soff += c;
        }
        tileDesc[s] = d;
    }
}

// ---- K3: gather x -> xg3[j][slot][i] bf16 (64-B rows), LDS transpose ----
__global__ __launch_bounds__(256) void k_xg3(const float* __restrict__ x,
                                             const int* __restrict__ tokmap,
                                             unsigned short* __restrict__ xg3) {
    __shared__ float tile[8][1056];                 // pad +1 per 32
    int s0 = blockIdx.x * 8;
    int tid = threadIdx.x;
    int r = tid >> 5, c = tid & 31;
    int tok = tokmap[s0 + r];
    const float* xr = x + (size_t)tok * DIM;
    #pragma unroll
    for (int u = 0; u < 8; ++u) {
        int d = u * 128 + c * 4;
        float4 v = *(const float4*)&xr[d];
        int d2 = d + (d >> 5);
        tile[r][d2 + 0] = v.x; tile[r][d2 + 1] = v.y;
        tile[r][d2 + 2] = v.z; tile[r][d2 + 3] = v.w;
    }
    __syncthreads();
    int sl = tid >> 5, j = tid & 31;
    float v[32];
    #pragma unroll
    for (int i = 0; i < 32; ++i) v[i] = tile[sl][i * 33 + j];
    unsigned short* orow = xg3 + ((size_t)j * NTOK + s0 + sl) * 32;
    #pragma unroll
    for (int ic = 0; ic < 4; ++ic) {
        uint4 pk;
        pk.x = (uint32_t)f2bf(v[ic * 8 + 0]) | ((uint32_t)f2bf(v[ic * 8 + 1]) << 16);
        pk.y = (uint32_t)f2bf(v[ic * 8 + 2]) | ((uint32_t)f2bf(v[ic * 8 + 3]) << 16);
        pk.z = (uint32_t)f2bf(v[ic * 8 + 4]) | ((uint32_t)f2bf(v[ic * 8 + 5]) << 16);
        pk.w = (uint32_t)f2bf(v[ic * 8 + 6]) | ((uint32_t)f2bf(v[ic * 8 + 7]) << 16);
        *(uint4*)(orow + ic * 8) = pk;
    }
}

// ---- K4: MFMA z -> zbuf[kloc][e][joct][slot][8 jj] bf16 (full-line writes) ----
__global__ __launch_bounds__(256) void k_z(const unsigned short* __restrict__ w1m,
                                           const unsigned short* __restrict__ xg3,
                                           const int* __restrict__ tokmap,
                                           const float* __restrict__ wgt,
                                           const int4* __restrict__ tileDesc,
                                           unsigned short* __restrict__ zbuf,
                                           int kb0, int nkb) {
    int bid = blockIdx.x;
    int joct = bid & 3;
    int tb   = bid >> 2;

    int4 td = tileDesc[tb];
    int p = td.x, s0 = td.y, cnt = td.z;
    if (p < 0) return;

    int a0 = 0, r0 = p;
    while (r0 >= 7 - a0) { r0 -= 7 - a0; ++a0; }
    int ea = a0, eb = a0 + 1 + r0;

    int tid = threadIdx.x;
    int mt = tid >> 6, l = tid & 63;
    int lr = l & 15, lg = l >> 4;
    int e_lane = lr >> 3, kk = lr & 7;
    int my_e = e_lane ? eb : ea;

    float gs[4];
    #pragma unroll
    for (int r = 0; r < 4; ++r) {
        int tok = tokmap[min(s0 + mt * 16 + lg * 4 + r, NTOK - 1)];
        float2 wv = *(const float2*)&wgt[tok * 2];
        gs[r] = e_lane ? wv.y : wv.x;
    }

    // A fragments: x rows for 8 j's (k-label: i = lg*8 + elem)
    bf16x8 a[8];
    int srow = min(s0 + mt * 16 + lr, NTOK - 1);
    #pragma unroll
    for (int jj = 0; jj < 8; ++jj) {
        int j = joct * 8 + jj;
        a[jj] = *(const bf16x8*)(xg3 + ((size_t)j * NTOK + srow) * 32 + lg * 8);
    }

    const f32x4 zero4 = {0.f, 0.f, 0.f, 0.f};
    for (int kbi = 0; kbi < nkb; ++kbi) {
        int kb = kb0 + kbi;
        f32x4 dj[8];
        #pragma unroll
        for (int jj = 0; jj < 8; ++jj) {
            int j = joct * 8 + jj;
            bf16x8 b = *(const bf16x8*)(w1m + (((size_t)(my_e * 32 + j) * 64) + kb * 8 + kk) * 32 + lg * 8);
            dj[jj] = __builtin_amdgcn_mfma_f32_16x16x32_bf16(a[jj], b, zero4, 0, 0, 0);
        }
        int kloc = kbi * 8 + kk;
        #pragma unroll
        for (int r = 0; r < 4; ++r) {
            int t = mt * 16 + lg * 4 + r;
            if (t < cnt) {
                float g = gs[r];
                uint4 pk;
                pk.x = (uint32_t)f2bf(dj[0][r] * g) | ((uint32_t)f2bf(dj[1][r] * g) << 16);
                pk.y = (uint32_t)f2bf(dj[2][r] * g) | ((uint32_t)f2bf(dj[3][r] * g) << 16);
                pk.z = (uint32_t)f2bf(dj[4][r] * g) | ((uint32_t)f2bf(dj[5][r] * g) << 16);
                pk.w = (uint32_t)f2bf(dj[6][r] * g) | ((uint32_t)f2bf(dj[7][r] * g) << 16);
                *(uint4*)(zbuf + (((size_t)(kloc * 2 + e_lane) * 4 + joct) * NTOK + s0 + t) * 8) = pk;
            }
        }
    }
}

// ---- K5: MFMA y — direct coalesced A-frag loads, no LDS, plain stores ----
__global__ __launch_bounds__(256, 4) void k_y(const unsigned short* __restrict__ w2m,
                                              const float* __restrict__ bias,
                                              const unsigned short* __restrict__ zbuf,
                                              const int* __restrict__ tokmap,
                                              const int4* __restrict__ tileDesc,
                                              float* __restrict__ out,
                                              int kb0, int nkbl) {
    int bid = blockIdx.x;
    int kbL = bid % nkbl;
    int tb  = bid / nkbl;

    int4 td = tileDesc[tb];
    int p = td.x, s0 = td.y, cnt = td.z;
    if (p < 0) return;

    int a0 = 0, r0 = p;
    while (r0 >= 7 - a0) { r0 -= 7 - a0; ++a0; }
    int ea = a0, eb = a0 + 1 + r0;

    int tid = threadIdx.x;
    int mt = tid >> 6, l = tid & 63;
    int lr = l & 15, lg = l >> 4;
    int kg8 = (kb0 + kbL) * 8;

    // A-fragments: zbuf[kloc][e][joct=lg][t=tA][jj 0..7]; 16 lanes -> 256 B contiguous
    int tA = min(s0 + mt * 16 + lr, NTOK - 1);
    bf16x8 az[8][2];
    #pragma unroll
    for (int k = 0; k < 8; ++k) {
        int kloc = kbL * 8 + k;
        az[k][0] = *(const bf16x8*)(zbuf + (((size_t)(kloc * 2 + 0) * 4 + lg) * NTOK + tA) * 8);
        az[k][1] = *(const bf16x8*)(zbuf + (((size_t)(kloc * 2 + 1) * 4 + lg) * NTOK + tA) * 8);
    }

    int tokm[4];
    #pragma unroll
    for (int r = 0; r < 4; ++r)
        tokm[r] = tokmap[min(s0 + mt * 16 + lg * 4 + r, NTOK - 1)];

    const f32x4 zero4 = {0.f, 0.f, 0.f, 0.f};
    #pragma unroll 2
    for (int k = 0; k < 8; ++k) {
        int kg = kg8 + k;
        f32x4 acc[4];
        #pragma unroll
        for (int nt = 0; nt < 4; ++nt) acc[nt] = zero4;
        #pragma unroll
        for (int nt = 0; nt < 4; ++nt) {
            bf16x8 b0 = *(const bf16x8*)(w2m + (((size_t)ea * 64 + kg) * 64 + nt * 16 + lr) * 32 + lg * 8);
            acc[nt] = __builtin_amdgcn_mfma_f32_16x16x32_bf16(az[k][0], b0, acc[nt], 0, 0, 0);
            bf16x8 b1 = *(const bf16x8*)(w2m + (((size_t)eb * 64 + kg) * 64 + nt * 16 + lr) * 32 + lg * 8);
            acc[nt] = __builtin_amdgcn_mfma_f32_16x16x32_bf16(az[k][1], b1, acc[nt], 0, 0, 0);
        }
        #pragma unroll
        for (int nt = 0; nt < 4; ++nt) {
            float bv = bias[kg * 64 + nt * 16 + lr];
            #pragma unroll
            for (int r = 0; r < 4; ++r) {
                int t2 = mt * 16 + lg * 4 + r;
                if (t2 < cnt)
                    out[(size_t)tokm[r] * OUTD + (size_t)kg * 64 + nt * 16 + lr] = acc[nt][r] + bv;
            }
        }
    }
}

extern "C" void kernel_launch(void* const* d_in, const int* in_sizes, int n_in,
                              void* d_out, int out_size, void* d_ws, size_t ws_size,
                              hipStream_t stream) {
    const float* x  = (const float*)d_in[0];
    const float* Wg = (const float*)d_in[1];
    const float* W1 = (const float*)d_in[2];
    const float* W2 = (const float*)d_in[3];
    const float* b  = (const float*)d_in[4];
    float* out = (float*)d_out;

    unsigned short* w1m = (unsigned short*)d_ws;            // 1 MB
    unsigned short* w2m = w1m + 524288;                     // 2 MB
    unsigned short* xg3 = w2m + 1048576;                    // 16 MB
    unsigned short* zbuf = xg3 + 8388608;                   // 64 MB (or 32 MB two-pass)

    size_t need1 = ((size_t)524288 + 1048576 + 8388608 + 33554432) * 2 +
                   ((size_t)NTOK + 2 * NTOK + 32) * 4 + (size_t)MAXTILES * 16;
    int onep = (ws_size >= need1) ? 1 : 0;
    size_t zwords = (size_t)(onep ? 33554432 : 16777216);

    int*   tokmap   = (int*)(zbuf + zwords);
    float* wgt      = (float*)(tokmap + NTOK);
    int*   pairCnt  = (int*)(wgt + 2 * NTOK);
    int4*  tileDesc = (int4*)(pairCnt + 32);
    int*   bucket   = (int*)xg3;                            // aliased: dead before k_xg3 runs

    k_wm   <<<6144, 256, 0, stream>>>(W1, W2, w1m, w2m, pairCnt);
    k_gate <<<2048, 256, 0, stream>>>(x, Wg, pairCnt, bucket, wgt);
    k_slots<<<32,   256, 0, stream>>>(pairCnt, bucket, tokmap, tileDesc);
    k_xg3  <<<1024, 256, 0, stream>>>(x, tokmap, xg3);

    if (onep) {
        k_z<<<MAXTILES * 4, 256, 0, stream>>>(w1m, xg3, tokmap, wgt, tileDesc, zbuf, 0, 8);
        k_y<<<MAXTILES * 8, 256, 0, stream>>>(w2m, b, zbuf, tokmap, tileDesc, out, 0, 8);
    } else {
        for (int h = 0; h < 2; ++h) {
            k_z<<<MAXTILES * 4, 256, 0, stream>>>(w1m, xg3, tokmap, wgt, tileDesc, zbuf, h * 4, 4);
            k_y<<<MAXTILES * 4, 256, 0, stream>>>(w2m, b, zbuf, tokmap, tileDesc, out, h * 4, 4);
        }
    }
}

// Round 9
// 172.655 us; speedup vs baseline: 1.3025x; 1.3025x over previous
//
#include <hip/hip_runtime.h>
#include <stdint.h>

#define NTOK 8192
#define DIM  1024
#define NE   8
#define NPAIR 28
#define OUTD 4096
#define MAXT16 539   // >= sum_p ceil(cnt_p/16): 512 + 27 worst case

typedef __attribute__((ext_vector_type(8))) short bf16x8;
typedef __attribute__((ext_vector_type(4))) float f32x4;

static __device__ __forceinline__ unsigned short f2bf(float f) {
    uint32_t u = __float_as_uint(f);
    u += 0x7fffu + ((u >> 16) & 1u);     // RNE
    return (unsigned short)(u >> 16);
}

// ---- K0: weight repacks to bf16 (+ zero pairCnt; runs FIRST) ----
// w1m[e][j][k][i]  i contiguous : 524288 elems
// w2m[e][k][l][j]  j contiguous : 1048576 elems
__global__ __launch_bounds__(256) void k_wm(const float* __restrict__ W1,
                                            const float* __restrict__ W2,
                                            unsigned short* __restrict__ w1m,
                                            unsigned short* __restrict__ w2m,
                                            int* __restrict__ pairCnt) {
    int t = blockIdx.x * 256 + threadIdx.x;
    if (blockIdx.x == 0 && threadIdx.x < 32) pairCnt[threadIdx.x] = 0;
    if (t < 524288) {
        int i = t & 31, k = (t >> 5) & 63, j = (t >> 11) & 31, e = (t >> 16) & 7;
        w1m[t] = f2bf(W1[(((j * 32 + i) * 64 + k) * 8) + e]);
    } else {
        int t2 = t - 524288;
        int j = t2 & 31, l = (t2 >> 5) & 63, k = (t2 >> 11) & 63, e = (t2 >> 17) & 7;
        w2m[t2] = f2bf(W2[(((e * 64 + k) * 32 + j) * 64) + l]);
    }
}

// ---- K1: gate (fp32) + pair bucketing ----
__global__ __launch_bounds__(256) void k_gate(const float* __restrict__ x,
                                              const float* __restrict__ Wg,
                                              int* __restrict__ pairCnt,
                                              int* __restrict__ bucket,
                                              float* __restrict__ wgt) {
    __shared__ float sWg[NE][DIM];
    int tid = threadIdx.x;
    #pragma unroll
    for (int u = 0; u < 8; ++u) {
        int idx = u * 1024 + tid * 4;
        *(float4*)&sWg[0][idx] = *(const float4*)&Wg[idx];
    }
    __syncthreads();
    int w = tid >> 6, lane = tid & 63;
    int tok = blockIdx.x * 4 + w;
    float acc[NE];
    #pragma unroll
    for (int e = 0; e < NE; ++e) acc[e] = 0.f;
    const float* xr = x + (size_t)tok * DIM;
    #pragma unroll
    for (int c = 0; c < 4; ++c) {
        float4 xv = *(const float4*)&xr[c * 256 + lane * 4];
        #pragma unroll
        for (int e = 0; e < NE; ++e) {
            float4 wv = *(const float4*)&sWg[e][c * 256 + lane * 4];
            acc[e] += xv.x * wv.x + xv.y * wv.y + xv.z * wv.z + xv.w * wv.w;
        }
    }
    #pragma unroll
    for (int e = 0; e < NE; ++e)
        #pragma unroll
        for (int off = 32; off > 0; off >>= 1)
            acc[e] += __shfl_xor(acc[e], off, 64);
    if (lane == 0) {
        int i1 = 0; float v1 = acc[0];
        for (int e = 1; e < NE; ++e) if (acc[e] > v1) { v1 = acc[e]; i1 = e; }
        int i2 = -1; float v2 = -3.4e38f;
        for (int e = 0; e < NE; ++e) { if (e == i1) continue; if (acc[e] > v2) { v2 = acc[e]; i2 = e; } }
        float ex = expf(v2 - v1);
        float s  = 1.f / (1.f + ex);
        float w1v = s + 1e-6f;
        float w2v = ex * s + 1e-6f;
        int ea = min(i1, i2), eb = max(i1, i2);
        float wa = (i1 < i2) ? w1v : w2v;
        float wb = (i1 < i2) ? w2v : w1v;
        wgt[tok * 2 + 0] = wa;
        wgt[tok * 2 + 1] = wb;
        int pid = ea * 7 - (ea * (ea - 1)) / 2 + (eb - ea - 1);
        int pos = atomicAdd(&pairCnt[pid], 1);
        bucket[pid * NTOK + pos] = tok;
    }
}

// ---- K2: slot -> token map + 16-token tile descriptors ----
__global__ __launch_bounds__(256) void k_slots(const int* __restrict__ pairCnt,
                                               const int* __restrict__ bucket,
                                               int* __restrict__ tokmap,
                                               int4* __restrict__ tileDesc) {
    int s = blockIdx.x * 256 + threadIdx.x;
    {
        int off = 0;
        for (int p = 0; p < NPAIR; ++p) {
            int c = pairCnt[p];
            if (s < off + c) { tokmap[s] = bucket[p * NTOK + (s - off)]; break; }
            off += c;
        }
    }
    if (s < MAXT16) {
        int4 d; d.x = -1; d.y = 0; d.z = 0; d.w = 0;
        int toff = 0, soff = 0;
        for (int q = 0; q < NPAIR; ++q) {
            int c = pairCnt[q];
            int nt = (c + 15) >> 4;
            if (d.x < 0 && s < toff + nt) {
                int lt = s - toff;
                d.x = q;
                d.y = soff + lt * 16;
                d.z = min(16, c - lt * 16);
            }
            toff += nt; soff += c;
        }
        tileDesc[s] = d;
    }
}

// ---- K3: gather x -> xg3[j][slot][i] bf16 (64-B rows), LDS transpose ----
__global__ __launch_bounds__(256) void k_xg3(const float* __restrict__ x,
                                             const int* __restrict__ tokmap,
                                             unsigned short* __restrict__ xg3) {
    __shared__ float tile[8][1056];                 // pad +1 per 32
    int s0 = blockIdx.x * 8;
    int tid = threadIdx.x;
    int r = tid >> 5, c = tid & 31;
    int tok = tokmap[s0 + r];
    const float* xr = x + (size_t)tok * DIM;
    #pragma unroll
    for (int u = 0; u < 8; ++u) {
        int d = u * 128 + c * 4;
        float4 v = *(const float4*)&xr[d];
        int d2 = d + (d >> 5);
        tile[r][d2 + 0] = v.x; tile[r][d2 + 1] = v.y;
        tile[r][d2 + 2] = v.z; tile[r][d2 + 3] = v.w;
    }
    __syncthreads();
    int sl = tid >> 5, j = tid & 31;
    float v[32];
    #pragma unroll
    for (int i = 0; i < 32; ++i) v[i] = tile[sl][i * 33 + j];
    unsigned short* orow = xg3 + ((size_t)j * NTOK + s0 + sl) * 32;
    #pragma unroll
    for (int ic = 0; ic < 4; ++ic) {
        uint4 pk;
        pk.x = (uint32_t)f2bf(v[ic * 8 + 0]) | ((uint32_t)f2bf(v[ic * 8 + 1]) << 16);
        pk.y = (uint32_t)f2bf(v[ic * 8 + 2]) | ((uint32_t)f2bf(v[ic * 8 + 3]) << 16);
        pk.z = (uint32_t)f2bf(v[ic * 8 + 4]) | ((uint32_t)f2bf(v[ic * 8 + 5]) << 16);
        pk.w = (uint32_t)f2bf(v[ic * 8 + 6]) | ((uint32_t)f2bf(v[ic * 8 + 7]) << 16);
        *(uint4*)(orow + ic * 8) = pk;
    }
}

// ---- K4: fused BTT — phase1 z->LDS (XOR-swizzled), phase2 MFMA -> out ----
// 16-token tile per block; loops all 8 kb; z never touches global memory.
__global__ __launch_bounds__(256, 4) void k_fz(const unsigned short* __restrict__ w1m,
                                               const unsigned short* __restrict__ w2m,
                                               const unsigned short* __restrict__ xg3,
                                               const float* __restrict__ bias,
                                               const int* __restrict__ tokmap,
                                               const float* __restrict__ wgt,
                                               const int4* __restrict__ tileDesc,
                                               float* __restrict__ out) {
    __shared__ unsigned short zls[8][2][4][16][8];  // 16 KB: [kk][e][joct][tslot][jj]

    int4 td = tileDesc[blockIdx.x];
    int p = td.x, s0 = td.y, cnt = td.z;
    if (p < 0) return;

    int a0 = 0, r0 = p;
    while (r0 >= 7 - a0) { r0 -= 7 - a0; ++a0; }
    int ea = a0, eb = a0 + 1 + r0;

    int tid = threadIdx.x;
    int w = tid >> 6, l = tid & 63;
    int lr = l & 15, lg = l >> 4;
    int e_lane = lr >> 3, kk = lr & 7;
    int my_e = e_lane ? eb : ea;

    // gate scales + tokens, output-row indexed (t = lg*4 + r)
    float gs[4];
    int tokm[4];
    #pragma unroll
    for (int r = 0; r < 4; ++r) {
        int tok = tokmap[min(s0 + lg * 4 + r, NTOK - 1)];
        tokm[r] = tok;
        float2 wv = *(const float2*)&wgt[tok * 2];
        gs[r] = e_lane ? wv.y : wv.x;
    }

    // A fragments (x) for this wave's 8 j's — reused across all 8 kb
    bf16x8 a[8];
    int srow = min(s0 + lr, NTOK - 1);
    #pragma unroll
    for (int jj = 0; jj < 8; ++jj) {
        int j = w * 8 + jj;
        a[jj] = *(const bf16x8*)(xg3 + ((size_t)j * NTOK + srow) * 32 + lg * 8);
    }

    const f32x4 zero4 = {0.f, 0.f, 0.f, 0.f};

    for (int kb = 0; kb < 8; ++kb) {
        // ---- phase 1: z for this kb (wave w owns j-oct w) ----
        f32x4 dj[8];
        #pragma unroll
        for (int jj = 0; jj < 8; ++jj) {
            int j = w * 8 + jj;
            bf16x8 b = *(const bf16x8*)(w1m + (((size_t)(my_e * 32 + j) * 64) + kb * 8 + kk) * 32 + lg * 8);
            dj[jj] = __builtin_amdgcn_mfma_f32_16x16x32_bf16(a[jj], b, zero4, 0, 0, 0);
        }
        if (kb) __syncthreads();                    // prev phase2 done before overwrite
        #pragma unroll
        for (int r = 0; r < 4; ++r) {
            float g = gs[r];
            int ts = (lg * 4 + r) ^ kk;             // XOR swizzle: bank-floor writes/reads
            uint4 pk;
            pk.x = (uint32_t)f2bf(dj[0][r] * g) | ((uint32_t)f2bf(dj[1][r] * g) << 16);
            pk.y = (uint32_t)f2bf(dj[2][r] * g) | ((uint32_t)f2bf(dj[3][r] * g) << 16);
            pk.z = (uint32_t)f2bf(dj[4][r] * g) | ((uint32_t)f2bf(dj[5][r] * g) << 16);
            pk.w = (uint32_t)f2bf(dj[6][r] * g) | ((uint32_t)f2bf(dj[7][r] * g) << 16);
            *(uint4*)&zls[kk][e_lane][w][ts][0] = pk;
        }
        __syncthreads();

        // ---- phase 2: wave w = l-tile; contract je=64 per (k) ----
        #pragma unroll
        for (int k = 0; k < 8; ++k) {
            int kg = kb * 8 + k;
            bf16x8 az0 = *(const bf16x8*)&zls[k][0][lg][lr ^ k][0];
            bf16x8 az1 = *(const bf16x8*)&zls[k][1][lg][lr ^ k][0];
            f32x4 acc = zero4;
            bf16x8 b0 = *(const bf16x8*)(w2m + (((size_t)ea * 64 + kg) * 64 + w * 16 + lr) * 32 + lg * 8);
            acc = __builtin_amdgcn_mfma_f32_16x16x32_bf16(az0, b0, acc, 0, 0, 0);
            bf16x8 b1 = *(const bf16x8*)(w2m + (((size_t)eb * 64 + kg) * 64 + w * 16 + lr) * 32 + lg * 8);
            acc = __builtin_amdgcn_mfma_f32_16x16x32_bf16(az1, b1, acc, 0, 0, 0);
            float bv = bias[kg * 64 + w * 16 + lr];
            #pragma unroll
            for (int r = 0; r < 4; ++r) {
                if (lg * 4 + r < cnt)
                    __builtin_nontemporal_store(acc[r] + bv,
                        out + (size_t)tokm[r] * OUTD + (size_t)kg * 64 + w * 16 + lr);
            }
        }
    }
}

extern "C" void kernel_launch(void* const* d_in, const int* in_sizes, int n_in,
                              void* d_out, int out_size, void* d_ws, size_t ws_size,
                              hipStream_t stream) {
    const float* x  = (const float*)d_in[0];
    const float* Wg = (const float*)d_in[1];
    const float* W1 = (const float*)d_in[2];
    const float* W2 = (const float*)d_in[3];
    const float* b  = (const float*)d_in[4];
    float* out = (float*)d_out;

    unsigned short* w1m = (unsigned short*)d_ws;            // 1 MB
    unsigned short* w2m = w1m + 524288;                     // 2 MB
    unsigned short* xg3 = w2m + 1048576;                    // 16 MB
    int*   tokmap   = (int*)(xg3 + 8388608);                // 8192 i
    float* wgt      = (float*)(tokmap + NTOK);              // 16384 f
    int*   pairCnt  = (int*)(wgt + 2 * NTOK);               // 32 i
    int4*  tileDesc = (int4*)(pairCnt + 32);                // 539 int4
    int*   bucket   = (int*)xg3;                            // aliased: dead before k_xg3 runs

    k_wm   <<<6144, 256, 0, stream>>>(W1, W2, w1m, w2m, pairCnt);
    k_gate <<<2048, 256, 0, stream>>>(x, Wg, pairCnt, bucket, wgt);
    k_slots<<<32,   256, 0, stream>>>(pairCnt, bucket, tokmap, tileDesc);
    k_xg3  <<<1024, 256, 0, stream>>>(x, tokmap, xg3);
    k_fz   <<<MAXT16, 256, 0, stream>>>(w1m, w2m, xg3, b, tokmap, wgt, tileDesc, out);
}